// Round 2
// baseline (530.861 us; speedup 1.0000x reference)
//
#include <hip/hip_runtime.h>

#define HH 4
#define CC 128
#define NEG_SLOPE 0.2f
#define NPB 8

// ---------------- kernel 0: mean of edge_attr ----------------
__global__ void mean_reduce_kernel(const float* __restrict__ ea,
                                   float* __restrict__ out, int E) {
    float s = 0.f;
    for (int i = blockIdx.x * blockDim.x + threadIdx.x; i < E;
         i += gridDim.x * blockDim.x)
        s += ea[i];
    #pragma unroll
    for (int off = 32; off > 0; off >>= 1) s += __shfl_down(s, off, 64);
    __shared__ float wsum[4];
    int lane = threadIdx.x & 63, wid = threadIdx.x >> 6;
    if (lane == 0) wsum[wid] = s;
    __syncthreads();
    if (threadIdx.x == 0) {
        float t = 0.f;
        for (int w = 0; w < (int)(blockDim.x >> 6); ++w) t += wsum[w];
        atomicAdd(out, t);
    }
}

// ---------------- kernel P: pack weights into [bh][c][8] records ------------
// record k: 0:A=Wsrc[hc] 1:B=Wsrc[512+hc] 2:C=Wdst[hc] 3:D=Wdst[512+hc]
//           4:E=Wedge[hc] 5:F=bsrc[hc]+bdst[hc] 6:G=att[hc] 7:pad
__global__ __launch_bounds__(256) void pack_kernel(
    const float* __restrict__ Wsrc0, const float* __restrict__ bsrc0,
    const float* __restrict__ Wdst0, const float* __restrict__ bdst0,
    const float* __restrict__ Wedge0, const float* __restrict__ att0,
    const float* __restrict__ Wsrc1, const float* __restrict__ bsrc1,
    const float* __restrict__ Wdst1, const float* __restrict__ bdst1,
    const float* __restrict__ Wedge1, const float* __restrict__ att1,
    float* __restrict__ packed)
{
    int tid = blockIdx.x * 256 + threadIdx.x;
    if (tid >= 1024) return;
    int b = tid >> 9;
    int hc = tid & 511;
    int h = hc >> 7;
    int c = hc & 127;
    int bh = b * 4 + h;
    const float* Ws = b ? Wsrc1 : Wsrc0;
    const float* bs = b ? bsrc1 : bsrc0;
    const float* Wd = b ? Wdst1 : Wdst0;
    const float* bd = b ? bdst1 : bdst0;
    const float* We = b ? Wedge1 : Wedge0;
    const float* at = b ? att1 : att0;
    float* r = packed + ((size_t)(bh * 128 + c)) * 8;
    r[0] = Ws[hc];
    r[1] = Ws[512 + hc];
    r[2] = Wd[hc];
    r[3] = Wd[512 + hc];
    r[4] = We[hc];
    r[5] = bs[hc] + bd[hc];
    r[6] = at[hc];
    r[7] = 0.f;
}

// ---------------- kernel A: per-edge logits + scalar aggregation ------------
// S layout (interleaved): S[n*24 + bh*3 + comp], comp {0:p*xs0, 1:p*xs1, 2:p}
__global__ __launch_bounds__(256) void edge_kernel(
    const float* __restrict__ x,
    const int* __restrict__ ei,
    const float* __restrict__ eattr,
    const float* __restrict__ meansum,
    const float4* __restrict__ packed4,
    float* __restrict__ S, int N, int E)
{
    __shared__ __align__(16) float4 wlds[2048];  // 32 KB
    int t = threadIdx.x;
    #pragma unroll
    for (int i = 0; i < 8; ++i)
        wlds[t + i * 256] = packed4[t + i * 256];
    __syncthreads();

    int e = blockIdx.x * 256 + t;
    int Etot = E + N;
    if (e >= Etot) return;

    int src, dst;
    float ea;
    if (e < E) {
        src = ei[e];
        dst = ei[E + e];
        ea = eattr[e];
    } else {
        src = e - E;
        dst = src;
        ea = meansum[0] / (float)E;
    }
    float xs0 = x[2 * src], xs1 = x[2 * src + 1];
    float xd0 = x[2 * dst], xd1 = x[2 * dst + 1];

    float lg[8];
    #pragma unroll
    for (int bh = 0; bh < 8; ++bh) lg[bh] = 0.f;

    for (int c = 0; c < CC; ++c) {
        #pragma unroll
        for (int bh = 0; bh < 8; ++bh) {
            float4 w0 = wlds[bh * 256 + 2 * c];
            float4 w1 = wlds[bh * 256 + 2 * c + 1];
            float s = fmaf(xs0, w0.x,
                      fmaf(xs1, w0.y,
                      fmaf(xd0, w0.z,
                      fmaf(xd1, w0.w,
                      fmaf(ea, w1.x, w1.y)))));
            s = fmaxf(s, NEG_SLOPE * s);  // leaky relu
            lg[bh] = fmaf(s, w1.z, lg[bh]);
        }
    }

    float* Sp = S + (size_t)dst * 24;
    #pragma unroll
    for (int bh = 0; bh < 8; ++bh) {
        float p = __expf(lg[bh]);
        atomicAdd(Sp + bh * 3 + 0, p * xs0);
        atomicAdd(Sp + bh * 3 + 1, p * xs1);
        atomicAdd(Sp + bh * 3 + 2, p);
    }
}

// ---------------- kernel B: per-node reconstruction + fuse matvec -----------
__global__ __launch_bounds__(256) void node_kernel(
    const float* __restrict__ x,
    const float* __restrict__ S,
    const float* __restrict__ Wsrc0, const float* __restrict__ bsrc0,
    const float* __restrict__ bias0, const float* __restrict__ Wres0,
    const float* __restrict__ Wsrc1, const float* __restrict__ bsrc1,
    const float* __restrict__ bias1, const float* __restrict__ Wres1,
    const float* __restrict__ Wfuse, const float* __restrict__ bfuse,
    float* __restrict__ out, int N)
{
    __shared__ __align__(16) float hbuf[NPB][2 * CC];
    int t = threadIdx.x;
    int c = t & (CC - 1);
    int half = t >> 7;  // 0 or 1
    int n0 = blockIdx.x * NPB;

    // per-channel weights (independent of node)
    float w00[HH], w01[HH], wb0[HH], w10[HH], w11[HH], wb1[HH];
    #pragma unroll
    for (int h = 0; h < HH; ++h) {
        w00[h] = Wsrc0[h * CC + c];
        w01[h] = Wsrc0[512 + h * CC + c];
        wb0[h] = bsrc0[h * CC + c];
        w10[h] = Wsrc1[h * CC + c];
        w11[h] = Wsrc1[512 + h * CC + c];
        wb1[h] = bsrc1[h * CC + c];
    }
    float bi0 = bias0[c], bi1 = bias1[c];
    float r00 = Wres0[c], r01 = Wres0[CC + c];
    float r10 = Wres1[c], r11 = Wres1[CC + c];

    // phase 1: build h0/h1 for NPB nodes
    for (int ni = half; ni < NPB; ni += 2) {
        int n = n0 + ni;
        if (n < N) {
            float x0 = x[2 * n], x1 = x[2 * n + 1];
            const float* Sp = S + (size_t)n * 24;
            float h0v, h1v;
            {
                float acc = 0.f;
                #pragma unroll
                for (int h = 0; h < HH; ++h) {
                    float s0 = Sp[h * 3 + 0];
                    float s1 = Sp[h * 3 + 1];
                    float sb = Sp[h * 3 + 2];
                    float num = fmaf(w00[h], s0, fmaf(w01[h], s1, wb0[h] * sb));
                    acc += num / (sb + 1e-16f);
                }
                float o = fmaxf(acc * 0.25f + bi0, 0.f);
                h0v = o + x0 * r00 + x1 * r01;
            }
            {
                float acc = 0.f;
                #pragma unroll
                for (int h = 0; h < HH; ++h) {
                    float s0 = Sp[12 + h * 3 + 0];
                    float s1 = Sp[12 + h * 3 + 1];
                    float sb = Sp[12 + h * 3 + 2];
                    float num = fmaf(w10[h], s0, fmaf(w11[h], s1, wb1[h] * sb));
                    acc += num / (sb + 1e-16f);
                }
                float o = fmaxf(acc * 0.25f + bi1, 0.f);
                h1v = o + x0 * r10 + x1 * r11;
            }
            hbuf[ni][c] = h0v;
            hbuf[ni][CC + c] = h1v;
        }
    }
    __syncthreads();

    // phase 2: fuse matvec, each thread handles 4 nodes at channel c
    float acc[4];
    float bf = bfuse[c];
    #pragma unroll
    for (int j = 0; j < 4; ++j) acc[j] = bf;

    for (int i = 0; i < 2 * CC; i += 4) {
        float wv0 = Wfuse[(i + 0) * CC + c];
        float wv1 = Wfuse[(i + 1) * CC + c];
        float wv2 = Wfuse[(i + 2) * CC + c];
        float wv3 = Wfuse[(i + 3) * CC + c];
        #pragma unroll
        for (int j = 0; j < 4; ++j) {
            int ni = half * 4 + j;
            float4 hv = *reinterpret_cast<const float4*>(&hbuf[ni][i]);
            acc[j] = fmaf(hv.x, wv0, fmaf(hv.y, wv1,
                     fmaf(hv.z, wv2, fmaf(hv.w, wv3, acc[j]))));
        }
    }
    #pragma unroll
    for (int j = 0; j < 4; ++j) {
        int n = n0 + half * 4 + j;
        if (n < N) out[n * CC + c] = fmaxf(acc[j], 0.f);
    }
}

extern "C" void kernel_launch(void* const* d_in, const int* in_sizes, int n_in,
                              void* d_out, int out_size, void* d_ws, size_t ws_size,
                              hipStream_t stream) {
    const float* x      = (const float*)d_in[0];
    const int*   ei     = (const int*)d_in[1];
    const float* eattr  = (const float*)d_in[2];
    const float* Wsrc0  = (const float*)d_in[3];
    const float* bsrc0  = (const float*)d_in[4];
    const float* Wdst0  = (const float*)d_in[5];
    const float* bdst0  = (const float*)d_in[6];
    const float* Wedge0 = (const float*)d_in[7];
    const float* att0   = (const float*)d_in[8];
    const float* bias0  = (const float*)d_in[9];
    const float* Wres0  = (const float*)d_in[10];
    const float* Wsrc1  = (const float*)d_in[11];
    const float* bsrc1  = (const float*)d_in[12];
    const float* Wdst1  = (const float*)d_in[13];
    const float* bdst1  = (const float*)d_in[14];
    const float* Wedge1 = (const float*)d_in[15];
    const float* att1   = (const float*)d_in[16];
    const float* bias1  = (const float*)d_in[17];
    const float* Wres1  = (const float*)d_in[18];
    const float* Wfuse  = (const float*)d_in[19];
    const float* bfuse  = (const float*)d_in[20];
    float* out = (float*)d_out;

    int N = in_sizes[0] / 2;   // x is (N,2)
    int E = in_sizes[1] / 2;   // edge_index is (2,E)

    float* meansum = (float*)d_ws;
    float* S = (float*)((char*)d_ws + 256);
    size_t S_bytes = (size_t)24 * N * sizeof(float);
    float* packed = (float*)((char*)d_ws + 256 + S_bytes);

    hipMemsetAsync(d_ws, 0, 256 + S_bytes, stream);

    mean_reduce_kernel<<<64, 256, 0, stream>>>(eattr, meansum, E);

    pack_kernel<<<4, 256, 0, stream>>>(
        Wsrc0, bsrc0, Wdst0, bdst0, Wedge0, att0,
        Wsrc1, bsrc1, Wdst1, bdst1, Wedge1, att1, packed);

    int Etot = E + N;
    edge_kernel<<<(Etot + 255) / 256, 256, 0, stream>>>(
        x, ei, eattr, meansum, (const float4*)packed, S, N, E);

    node_kernel<<<(N + NPB - 1) / NPB, 256, 0, stream>>>(
        x, S,
        Wsrc0, bsrc0, bias0, Wres0,
        Wsrc1, bsrc1, bias1, Wres1,
        Wfuse, bfuse, out, N);
}

// Round 4
// 228.988 us; speedup vs baseline: 2.3183x; 2.3183x over previous
//
#include <hip/hip_runtime.h>

#define HH 4
#define CC 128
#define NEG_SLOPE 0.2f
#define NPB 8

static inline size_t roundup256(size_t x) { return (x + 255) & ~(size_t)255; }

// ---------------- kernel 0: mean of edge_attr ----------------
__global__ void mean_reduce_kernel(const float* __restrict__ ea,
                                   float* __restrict__ out, int E) {
    float s = 0.f;
    for (int i = blockIdx.x * blockDim.x + threadIdx.x; i < E;
         i += gridDim.x * blockDim.x)
        s += ea[i];
    #pragma unroll
    for (int off = 32; off > 0; off >>= 1) s += __shfl_down(s, off, 64);
    __shared__ float wsum[4];
    int lane = threadIdx.x & 63, wid = threadIdx.x >> 6;
    if (lane == 0) wsum[wid] = s;
    __syncthreads();
    if (threadIdx.x == 0) {
        float t = 0.f;
        for (int w = 0; w < (int)(blockDim.x >> 6); ++w) t += wsum[w];
        atomicAdd(out, t);
    }
}

// ---------------- kernel P: pack weights into [bh][c][8] records ------------
__global__ __launch_bounds__(256) void pack_kernel(
    const float* __restrict__ Wsrc0, const float* __restrict__ bsrc0,
    const float* __restrict__ Wdst0, const float* __restrict__ bdst0,
    const float* __restrict__ Wedge0, const float* __restrict__ att0,
    const float* __restrict__ Wsrc1, const float* __restrict__ bsrc1,
    const float* __restrict__ Wdst1, const float* __restrict__ bdst1,
    const float* __restrict__ Wedge1, const float* __restrict__ att1,
    float* __restrict__ packed)
{
    int tid = blockIdx.x * 256 + threadIdx.x;
    if (tid >= 1024) return;
    int b = tid >> 9;
    int hc = tid & 511;
    int h = hc >> 7;
    int c = hc & 127;
    int bh = b * 4 + h;
    const float* Ws = b ? Wsrc1 : Wsrc0;
    const float* bs = b ? bsrc1 : bsrc0;
    const float* Wd = b ? Wdst1 : Wdst0;
    const float* bd = b ? bdst1 : bdst0;
    const float* We = b ? Wedge1 : Wedge0;
    const float* at = b ? att1 : att0;
    float* r = packed + ((size_t)(bh * 128 + c)) * 8;
    r[0] = Ws[hc];
    r[1] = Ws[512 + hc];
    r[2] = Wd[hc];
    r[3] = Wd[512 + hc];
    r[4] = We[hc];
    r[5] = bs[hc] + bd[hc];
    r[6] = at[hc];
    r[7] = 0.f;
}

// ---------------- CSR build: histogram ----------------
__global__ __launch_bounds__(256) void hist_kernel(const int* __restrict__ ei,
                                                   int* __restrict__ cnt, int E) {
    int e = blockIdx.x * 256 + threadIdx.x;
    if (e < E) atomicAdd(&cnt[ei[E + e]], 1);
}

// ---------------- CSR build: exclusive scan (single block) ----------------
__global__ __launch_bounds__(1024) void scan_kernel(const int* __restrict__ cnt,
                                                    int* __restrict__ rowptr, int N) {
    const int CH = 32;  // covers N up to 32768
    int t = threadIdx.x;
    int base = t * CH;
    int local[CH];
    int s = 0;
    #pragma unroll
    for (int i = 0; i < CH; ++i) {
        int idx = base + i;
        int v = (idx < N) ? cnt[idx] : 0;
        local[i] = s;
        s += v;
    }
    __shared__ int sums[1024];
    sums[t] = s;
    __syncthreads();
    for (int off = 1; off < 1024; off <<= 1) {
        int v = (t >= off) ? sums[t - off] : 0;
        __syncthreads();
        sums[t] += v;
        __syncthreads();
    }
    int excl = sums[t] - s;
    #pragma unroll
    for (int i = 0; i < CH; ++i) {
        int idx = base + i;
        if (idx < N) rowptr[idx] = excl + local[i];
    }
    if (t == 1023) rowptr[N] = excl + s;
}

// ---------------- CSR build: scatter {src, e} ----------------
__global__ __launch_bounds__(256) void scatter_kernel(
    const int* __restrict__ ei, const int* __restrict__ rowptr,
    int* __restrict__ cur, int2* __restrict__ rec, int E) {
    int e = blockIdx.x * 256 + threadIdx.x;
    if (e >= E) return;
    int dst = ei[E + e];
    int pos = rowptr[dst] + atomicAdd(&cur[dst], 1);
    rec[pos] = make_int2(ei[e], e);
}

// ---------------- kernel A: per-edge logits (no atomics), 2 edges/thread ----
__global__ __launch_bounds__(256) void logits_kernel(
    const float* __restrict__ x,
    const int* __restrict__ ei,
    const float* __restrict__ eattr,
    const float* __restrict__ meansum,
    const float4* __restrict__ packed4,
    float* __restrict__ lg8, int N, int E)
{
    __shared__ __align__(16) float4 wlds[2048];  // 32 KB
    int t = threadIdx.x;
    #pragma unroll
    for (int i = 0; i < 8; ++i)
        wlds[t + i * 256] = packed4[t + i * 256];
    __syncthreads();

    int Etot = E + N;
    int e0 = blockIdx.x * 512 + t;
    int e1 = e0 + 256;
    bool v0 = e0 < Etot, v1 = e1 < Etot;

    int srcA = 0, dstA = 0, srcB = 0, dstB = 0;
    float eaA = 0.f, eaB = 0.f;
    float mean_ea = meansum[0] / (float)E;
    if (v0) {
        if (e0 < E) { srcA = ei[e0]; dstA = ei[E + e0]; eaA = eattr[e0]; }
        else        { srcA = e0 - E; dstA = srcA; eaA = mean_ea; }
    }
    if (v1) {
        if (e1 < E) { srcB = ei[e1]; dstB = ei[E + e1]; eaB = eattr[e1]; }
        else        { srcB = e1 - E; dstB = srcB; eaB = mean_ea; }
    }
    float xs0a = x[2 * srcA], xs1a = x[2 * srcA + 1];
    float xd0a = x[2 * dstA], xd1a = x[2 * dstA + 1];
    float xs0b = x[2 * srcB], xs1b = x[2 * srcB + 1];
    float xd0b = x[2 * dstB], xd1b = x[2 * dstB + 1];

    float lgA[8], lgB[8];
    #pragma unroll
    for (int bh = 0; bh < 8; ++bh) { lgA[bh] = 0.f; lgB[bh] = 0.f; }

    for (int c = 0; c < CC; ++c) {
        #pragma unroll
        for (int bh = 0; bh < 8; ++bh) {
            float4 w0 = wlds[bh * 256 + 2 * c];
            float4 w1 = wlds[bh * 256 + 2 * c + 1];
            float sA = fmaf(xs0a, w0.x,
                       fmaf(xs1a, w0.y,
                       fmaf(xd0a, w0.z,
                       fmaf(xd1a, w0.w,
                       fmaf(eaA, w1.x, w1.y)))));
            sA = fmaxf(sA, NEG_SLOPE * sA);
            lgA[bh] = fmaf(sA, w1.z, lgA[bh]);
            float sB = fmaf(xs0b, w0.x,
                       fmaf(xs1b, w0.y,
                       fmaf(xd0b, w0.z,
                       fmaf(xd1b, w0.w,
                       fmaf(eaB, w1.x, w1.y)))));
            sB = fmaxf(sB, NEG_SLOPE * sB);
            lgB[bh] = fmaf(sB, w1.z, lgB[bh]);
        }
    }

    if (v0) {
        float4* o = (float4*)&lg8[(size_t)e0 * 8];
        o[0] = make_float4(lgA[0], lgA[1], lgA[2], lgA[3]);
        o[1] = make_float4(lgA[4], lgA[5], lgA[6], lgA[7]);
    }
    if (v1) {
        float4* o = (float4*)&lg8[(size_t)e1 * 8];
        o[0] = make_float4(lgB[0], lgB[1], lgB[2], lgB[3]);
        o[1] = make_float4(lgB[4], lgB[5], lgB[6], lgB[7]);
    }
}

// ---------------- kernel S: per-node gather, no atomics ----------------
// 8 lanes per node (lane = bh); S[n*24 + bh*3 + {0,1,2}] = {sum p*xs0, sum p*xs1, sum p}
__global__ __launch_bounds__(256) void nodeS_kernel(
    const float* __restrict__ x, const int* __restrict__ rowptr,
    const int2* __restrict__ rec, const float* __restrict__ lg8,
    float* __restrict__ S, int N, int E)
{
    int t = threadIdx.x;
    int g = t >> 3, bh = t & 7;
    int n = blockIdx.x * 32 + g;
    if (n >= N) return;
    int beg = rowptr[n], end = rowptr[n + 1];
    float s0 = 0.f, s1 = 0.f, sb = 0.f;
    for (int i = beg; i < end; ++i) {
        int2 r = rec[i];
        float p = __expf(lg8[(size_t)r.y * 8 + bh]);
        float xs0 = x[2 * r.x], xs1 = x[2 * r.x + 1];
        s0 = fmaf(p, xs0, s0);
        s1 = fmaf(p, xs1, s1);
        sb += p;
    }
    // self loop
    {
        float p = __expf(lg8[(size_t)(E + n) * 8 + bh]);
        s0 = fmaf(p, x[2 * n], s0);
        s1 = fmaf(p, x[2 * n + 1], s1);
        sb += p;
    }
    float* Sp = S + (size_t)n * 24 + bh * 3;
    Sp[0] = s0;
    Sp[1] = s1;
    Sp[2] = sb;
}

// ---------------- kernel B: per-node reconstruction + fuse matvec -----------
__global__ __launch_bounds__(256) void node_kernel(
    const float* __restrict__ x,
    const float* __restrict__ S,
    const float* __restrict__ Wsrc0, const float* __restrict__ bsrc0,
    const float* __restrict__ bias0, const float* __restrict__ Wres0,
    const float* __restrict__ Wsrc1, const float* __restrict__ bsrc1,
    const float* __restrict__ bias1, const float* __restrict__ Wres1,
    const float* __restrict__ Wfuse, const float* __restrict__ bfuse,
    float* __restrict__ out, int N)
{
    __shared__ __align__(16) float hbuf[NPB][2 * CC];
    int t = threadIdx.x;
    int c = t & (CC - 1);
    int half = t >> 7;  // 0 or 1
    int n0 = blockIdx.x * NPB;

    float w00[HH], w01[HH], wb0[HH], w10[HH], w11[HH], wb1[HH];
    #pragma unroll
    for (int h = 0; h < HH; ++h) {
        w00[h] = Wsrc0[h * CC + c];
        w01[h] = Wsrc0[512 + h * CC + c];
        wb0[h] = bsrc0[h * CC + c];
        w10[h] = Wsrc1[h * CC + c];
        w11[h] = Wsrc1[512 + h * CC + c];
        wb1[h] = bsrc1[h * CC + c];
    }
    float bi0 = bias0[c], bi1 = bias1[c];
    float r00 = Wres0[c], r01 = Wres0[CC + c];
    float r10 = Wres1[c], r11 = Wres1[CC + c];

    for (int ni = half; ni < NPB; ni += 2) {
        int n = n0 + ni;
        if (n < N) {
            float x0 = x[2 * n], x1 = x[2 * n + 1];
            const float* Sp = S + (size_t)n * 24;
            float h0v, h1v;
            {
                float acc = 0.f;
                #pragma unroll
                for (int h = 0; h < HH; ++h) {
                    float s0 = Sp[h * 3 + 0];
                    float s1 = Sp[h * 3 + 1];
                    float sb = Sp[h * 3 + 2];
                    float num = fmaf(w00[h], s0, fmaf(w01[h], s1, wb0[h] * sb));
                    acc += num / (sb + 1e-16f);
                }
                float o = fmaxf(acc * 0.25f + bi0, 0.f);
                h0v = o + x0 * r00 + x1 * r01;
            }
            {
                float acc = 0.f;
                #pragma unroll
                for (int h = 0; h < HH; ++h) {
                    float s0 = Sp[12 + h * 3 + 0];
                    float s1 = Sp[12 + h * 3 + 1];
                    float sb = Sp[12 + h * 3 + 2];
                    float num = fmaf(w10[h], s0, fmaf(w11[h], s1, wb1[h] * sb));
                    acc += num / (sb + 1e-16f);
                }
                float o = fmaxf(acc * 0.25f + bi1, 0.f);
                h1v = o + x0 * r10 + x1 * r11;
            }
            hbuf[ni][c] = h0v;
            hbuf[ni][CC + c] = h1v;
        }
    }
    __syncthreads();

    float acc[4];
    float bf = bfuse[c];
    #pragma unroll
    for (int j = 0; j < 4; ++j) acc[j] = bf;

    for (int i = 0; i < 2 * CC; i += 4) {
        float wv0 = Wfuse[(i + 0) * CC + c];
        float wv1 = Wfuse[(i + 1) * CC + c];
        float wv2 = Wfuse[(i + 2) * CC + c];
        float wv3 = Wfuse[(i + 3) * CC + c];
        #pragma unroll
        for (int j = 0; j < 4; ++j) {
            int ni = half * 4 + j;
            float4 hv = *reinterpret_cast<const float4*>(&hbuf[ni][i]);
            acc[j] = fmaf(hv.x, wv0, fmaf(hv.y, wv1,
                     fmaf(hv.z, wv2, fmaf(hv.w, wv3, acc[j]))));
        }
    }
    #pragma unroll
    for (int j = 0; j < 4; ++j) {
        int n = n0 + half * 4 + j;
        if (n < N) out[n * CC + c] = fmaxf(acc[j], 0.f);
    }
}

extern "C" void kernel_launch(void* const* d_in, const int* in_sizes, int n_in,
                              void* d_out, int out_size, void* d_ws, size_t ws_size,
                              hipStream_t stream) {
    const float* x      = (const float*)d_in[0];
    const int*   ei     = (const int*)d_in[1];
    const float* eattr  = (const float*)d_in[2];
    const float* Wsrc0  = (const float*)d_in[3];
    const float* bsrc0  = (const float*)d_in[4];
    const float* Wdst0  = (const float*)d_in[5];
    const float* bdst0  = (const float*)d_in[6];
    const float* Wedge0 = (const float*)d_in[7];
    const float* att0   = (const float*)d_in[8];
    const float* bias0  = (const float*)d_in[9];
    const float* Wres0  = (const float*)d_in[10];
    const float* Wsrc1  = (const float*)d_in[11];
    const float* bsrc1  = (const float*)d_in[12];
    const float* Wdst1  = (const float*)d_in[13];
    const float* bdst1  = (const float*)d_in[14];
    const float* Wedge1 = (const float*)d_in[15];
    const float* att1   = (const float*)d_in[16];
    const float* bias1  = (const float*)d_in[17];
    const float* Wres1  = (const float*)d_in[18];
    const float* Wfuse  = (const float*)d_in[19];
    const float* bfuse  = (const float*)d_in[20];
    float* out = (float*)d_out;

    int N = in_sizes[0] / 2;   // x is (N,2)
    int E = in_sizes[1] / 2;   // edge_index is (2,E)
    int Etot = E + N;

    // workspace layout
    size_t off = 0;
    float* meansum = (float*)((char*)d_ws + off);  off += 256;
    float* packed  = (float*)((char*)d_ws + off);  off += roundup256(8 * 128 * 8 * sizeof(float));
    float* S       = (float*)((char*)d_ws + off);  off += roundup256((size_t)24 * N * sizeof(float));
    size_t cnt_off = off;
    int*   cnt     = (int*)((char*)d_ws + off);    off += roundup256((size_t)N * sizeof(int));
    int*   cur     = (int*)((char*)d_ws + off);    size_t cur_end = off + (size_t)N * sizeof(int);
                                                   off += roundup256((size_t)N * sizeof(int));
    int*   rowptr  = (int*)((char*)d_ws + off);    off += roundup256((size_t)(N + 1) * sizeof(int));
    int2*  rec     = (int2*)((char*)d_ws + off);   off += roundup256((size_t)E * sizeof(int2));
    float* lg8     = (float*)((char*)d_ws + off);  off += roundup256((size_t)Etot * 8 * sizeof(float));

    hipMemsetAsync(meansum, 0, 256, stream);
    hipMemsetAsync((char*)d_ws + cnt_off, 0, cur_end - cnt_off, stream);

    mean_reduce_kernel<<<64, 256, 0, stream>>>(eattr, meansum, E);

    pack_kernel<<<4, 256, 0, stream>>>(
        Wsrc0, bsrc0, Wdst0, bdst0, Wedge0, att0,
        Wsrc1, bsrc1, Wdst1, bdst1, Wedge1, att1, packed);

    hist_kernel<<<(E + 255) / 256, 256, 0, stream>>>(ei, cnt, E);
    scan_kernel<<<1, 1024, 0, stream>>>(cnt, rowptr, N);
    scatter_kernel<<<(E + 255) / 256, 256, 0, stream>>>(ei, rowptr, cur, rec, E);

    logits_kernel<<<(Etot + 511) / 512, 256, 0, stream>>>(
        x, ei, eattr, meansum, (const float4*)packed, lg8, N, E);

    nodeS_kernel<<<(N + 31) / 32, 256, 0, stream>>>(x, rowptr, rec, lg8, S, N, E);

    node_kernel<<<(N + NPB - 1) / NPB, 256, 0, stream>>>(
        x, S,
        Wsrc0, bsrc0, bias0, Wres0,
        Wsrc1, bsrc1, bias1, Wres1,
        Wfuse, bfuse, out, N);
}

// Round 5
// 227.547 us; speedup vs baseline: 2.3330x; 1.0063x over previous
//
#include <hip/hip_runtime.h>

#define HH 4
#define CC 128
#define NEG_SLOPE 0.2f
#define NPB 8

typedef float v2f __attribute__((ext_vector_type(2)));

static inline size_t roundup256(size_t x) { return (x + 255) & ~(size_t)255; }

// ---------------- prep: mean(edge_attr) + in-degree histogram + weight pack --
__global__ __launch_bounds__(256) void prep_kernel(
    const int* __restrict__ ei, const float* __restrict__ eattr,
    float* __restrict__ meansum, int* __restrict__ cnt,
    const float* __restrict__ Wsrc0, const float* __restrict__ bsrc0,
    const float* __restrict__ Wdst0, const float* __restrict__ bdst0,
    const float* __restrict__ Wedge0, const float* __restrict__ att0,
    const float* __restrict__ Wsrc1, const float* __restrict__ bsrc1,
    const float* __restrict__ Wdst1, const float* __restrict__ bdst1,
    const float* __restrict__ Wedge1, const float* __restrict__ att1,
    float* __restrict__ packed, int E)
{
    int tid = blockIdx.x * 256 + threadIdx.x;
    float s = 0.f;
    if (tid < E) {
        atomicAdd(&cnt[ei[E + tid]], 1);
        s = eattr[tid];
    }
    // block-reduce s -> meansum
    #pragma unroll
    for (int off = 32; off > 0; off >>= 1) s += __shfl_down(s, off, 64);
    __shared__ float wsum[4];
    int lane = threadIdx.x & 63, wid = threadIdx.x >> 6;
    if (lane == 0) wsum[wid] = s;
    __syncthreads();
    if (threadIdx.x == 0)
        atomicAdd(meansum, wsum[0] + wsum[1] + wsum[2] + wsum[3]);

    // pack weights: record per (bh,c): A,B,C,D,E,F=bsrc+bdst,G=att,pad
    if (tid < 1024) {
        int b = tid >> 9;
        int hc = tid & 511;
        int c = hc & 127;
        int h = hc >> 7;
        int bh = b * 4 + h;
        const float* Ws = b ? Wsrc1 : Wsrc0;
        const float* bs = b ? bsrc1 : bsrc0;
        const float* Wd = b ? Wdst1 : Wdst0;
        const float* bd = b ? bdst1 : bdst0;
        const float* We = b ? Wedge1 : Wedge0;
        const float* at = b ? att1 : att0;
        float* r = packed + ((size_t)(bh * 128 + c)) * 8;
        r[0] = Ws[hc];
        r[1] = Ws[512 + hc];
        r[2] = Wd[hc];
        r[3] = Wd[512 + hc];
        r[4] = We[hc];
        r[5] = bs[hc] + bd[hc];
        r[6] = at[hc];
        r[7] = 0.f;
    }
}

// ---------------- scan: exclusive prefix over (cnt+1), seeds cur ------------
__global__ __launch_bounds__(1024) void scan_kernel(const int* __restrict__ cnt,
                                                    int* __restrict__ rowptr,
                                                    int* __restrict__ cur, int N) {
    const int CH = 32;  // covers N up to 32768
    int t = threadIdx.x;
    int base = t * CH;
    int local[CH];
    int s = 0;
    #pragma unroll
    for (int i = 0; i < CH; ++i) {
        int idx = base + i;
        int v = (idx < N) ? cnt[idx] + 1 : 0;  // +1 = self loop
        local[i] = s;
        s += v;
    }
    __shared__ int sums[1024];
    sums[t] = s;
    __syncthreads();
    for (int off = 1; off < 1024; off <<= 1) {
        int v = (t >= off) ? sums[t - off] : 0;
        __syncthreads();
        sums[t] += v;
        __syncthreads();
    }
    int excl = sums[t] - s;
    #pragma unroll
    for (int i = 0; i < CH; ++i) {
        int idx = base + i;
        if (idx < N) {
            int v = excl + local[i];
            rowptr[idx] = v;
            cur[idx] = v;
        }
    }
    if (t == 1023) rowptr[N] = excl + s;
}

// ---------------- scatter: build CSR records {src,dst,e} incl self loops ----
__global__ __launch_bounds__(256) void scatter_kernel(
    const int* __restrict__ ei, int* __restrict__ cur,
    int4* __restrict__ rec4, int N, int E) {
    int e = blockIdx.x * 256 + threadIdx.x;
    int Etot = E + N;
    if (e >= Etot) return;
    int src, dst;
    if (e < E) { src = ei[e]; dst = ei[E + e]; }
    else       { src = e - E; dst = src; }
    int pos = atomicAdd(&cur[dst], 1);
    rec4[pos] = make_int4(src, dst, e, 0);
}

// ---------------- logits: weights in registers, edges broadcast from LDS ----
// lane = bh*8 + cg; lane owns channels [cg*16, cg*16+16) as 8 v2f pairs.
// Writes p = exp(logit) at CSR position: p8[i*8+bh].
__global__ __launch_bounds__(256) void logits_kernel(
    const float* __restrict__ x,
    const float* __restrict__ eattr,
    const float* __restrict__ meansum,
    const int4* __restrict__ rec4,
    const float4* __restrict__ packed4,
    float* __restrict__ p8, int N, int E)
{
    __shared__ __align__(16) float edat[4][64][8];
    int t = threadIdx.x;
    int wid = t >> 6, lane = t & 63;
    int bh = lane >> 3, cg = lane & 7;
    int Etot = E + N;

    // per-lane weights: 7 coefs x 8 channel-pairs
    v2f Av[8], Bv[8], Cv[8], Dv[8], Ev[8], Fv[8], Gv[8];
    int cbase = bh * 128 + cg * 16;
    #pragma unroll
    for (int p = 0; p < 8; ++p) {
        float4 wa0 = packed4[(cbase + 2 * p) * 2];
        float4 wa1 = packed4[(cbase + 2 * p) * 2 + 1];
        float4 wb0 = packed4[(cbase + 2 * p + 1) * 2];
        float4 wb1 = packed4[(cbase + 2 * p + 1) * 2 + 1];
        Av[p] = (v2f){wa0.x, wb0.x};
        Bv[p] = (v2f){wa0.y, wb0.y};
        Cv[p] = (v2f){wa0.z, wb0.z};
        Dv[p] = (v2f){wa0.w, wb0.w};
        Ev[p] = (v2f){wa1.x, wb1.x};
        Fv[p] = (v2f){wa1.y, wb1.y};
        Gv[p] = (v2f){wa1.z, wb1.z};
    }

    float mean = meansum[0] / (float)E;
    int base = (blockIdx.x * 4 + wid) * 64;

    // stage 64 edges for this wave
    {
        int i = base + lane;
        int4 r = (i < Etot) ? rec4[i] : make_int4(0, 0, E, 0);
        const float2* x2 = (const float2*)x;
        float2 xs = x2[r.x];
        float2 xd = x2[r.y];
        float ea = (r.z < E) ? eattr[r.z] : mean;
        *(float4*)&edat[wid][lane][0] = make_float4(xs.x, xs.y, xd.x, xd.y);
        edat[wid][lane][4] = ea;
    }
    __syncthreads();
    if (base >= Etot) return;
    int jmax = min(64, Etot - base);

    for (int j = 0; j < jmax; ++j) {
        float4 xv = *(const float4*)&edat[wid][j][0];
        float eas = edat[wid][j][4];
        v2f xs0 = {xv.x, xv.x}, xs1 = {xv.y, xv.y};
        v2f xd0 = {xv.z, xv.z}, xd1 = {xv.w, xv.w};
        v2f eav = {eas, eas};
        v2f acc = {0.f, 0.f};
        #pragma unroll
        for (int p = 0; p < 8; ++p) {
            v2f u = Fv[p] + Ev[p] * eav;
            u += Av[p] * xs0;
            u += Bv[p] * xs1;
            u += Cv[p] * xd0;
            u += Dv[p] * xd1;
            v2f un = u * NEG_SLOPE;
            u = __builtin_elementwise_max(u, un);
            acc += Gv[p] * u;
        }
        float lg = acc.x + acc.y;
        lg += __shfl_xor(lg, 1);
        lg += __shfl_xor(lg, 2);
        lg += __shfl_xor(lg, 4);
        if (cg == 0) p8[(size_t)(base + j) * 8 + bh] = __expf(lg);
    }
}

// ---------------- nodeS: per-node gather (coalesced CSR reads) --------------
__global__ __launch_bounds__(256) void nodeS_kernel(
    const float* __restrict__ x, const int* __restrict__ rowptr,
    const int4* __restrict__ rec4, const float* __restrict__ p8,
    float* __restrict__ S, int N)
{
    int t = threadIdx.x;
    int g = t >> 3, bh = t & 7;
    int n = blockIdx.x * 32 + g;
    if (n >= N) return;
    int beg = rowptr[n], end = rowptr[n + 1];
    const float2* x2 = (const float2*)x;
    float s0 = 0.f, s1 = 0.f, sb = 0.f;
    for (int i = beg; i < end; ++i) {
        int src = rec4[i].x;
        float p = p8[(size_t)i * 8 + bh];
        float2 xs = x2[src];
        s0 = fmaf(p, xs.x, s0);
        s1 = fmaf(p, xs.y, s1);
        sb += p;
    }
    float* Sp = S + (size_t)n * 24 + bh * 3;
    Sp[0] = s0;
    Sp[1] = s1;
    Sp[2] = sb;
}

// ---------------- node: reconstruction + fuse matvec ------------------------
__global__ __launch_bounds__(256) void node_kernel(
    const float* __restrict__ x,
    const float* __restrict__ S,
    const float* __restrict__ Wsrc0, const float* __restrict__ bsrc0,
    const float* __restrict__ bias0, const float* __restrict__ Wres0,
    const float* __restrict__ Wsrc1, const float* __restrict__ bsrc1,
    const float* __restrict__ bias1, const float* __restrict__ Wres1,
    const float* __restrict__ Wfuse, const float* __restrict__ bfuse,
    float* __restrict__ out, int N)
{
    __shared__ __align__(16) float hbuf[NPB][2 * CC];
    int t = threadIdx.x;
    int c = t & (CC - 1);
    int half = t >> 7;  // 0 or 1
    int n0 = blockIdx.x * NPB;

    float w00[HH], w01[HH], wb0[HH], w10[HH], w11[HH], wb1[HH];
    #pragma unroll
    for (int h = 0; h < HH; ++h) {
        w00[h] = Wsrc0[h * CC + c];
        w01[h] = Wsrc0[512 + h * CC + c];
        wb0[h] = bsrc0[h * CC + c];
        w10[h] = Wsrc1[h * CC + c];
        w11[h] = Wsrc1[512 + h * CC + c];
        wb1[h] = bsrc1[h * CC + c];
    }
    float bi0 = bias0[c], bi1 = bias1[c];
    float r00 = Wres0[c], r01 = Wres0[CC + c];
    float r10 = Wres1[c], r11 = Wres1[CC + c];

    for (int ni = half; ni < NPB; ni += 2) {
        int n = n0 + ni;
        if (n < N) {
            float x0 = x[2 * n], x1 = x[2 * n + 1];
            const float* Sp = S + (size_t)n * 24;
            float h0v, h1v;
            {
                float acc = 0.f;
                #pragma unroll
                for (int h = 0; h < HH; ++h) {
                    float s0 = Sp[h * 3 + 0];
                    float s1 = Sp[h * 3 + 1];
                    float sb = Sp[h * 3 + 2];
                    float num = fmaf(w00[h], s0, fmaf(w01[h], s1, wb0[h] * sb));
                    acc += num / (sb + 1e-16f);
                }
                float o = fmaxf(acc * 0.25f + bi0, 0.f);
                h0v = o + x0 * r00 + x1 * r01;
            }
            {
                float acc = 0.f;
                #pragma unroll
                for (int h = 0; h < HH; ++h) {
                    float s0 = Sp[12 + h * 3 + 0];
                    float s1 = Sp[12 + h * 3 + 1];
                    float sb = Sp[12 + h * 3 + 2];
                    float num = fmaf(w10[h], s0, fmaf(w11[h], s1, wb1[h] * sb));
                    acc += num / (sb + 1e-16f);
                }
                float o = fmaxf(acc * 0.25f + bi1, 0.f);
                h1v = o + x0 * r10 + x1 * r11;
            }
            hbuf[ni][c] = h0v;
            hbuf[ni][CC + c] = h1v;
        }
    }
    __syncthreads();

    float acc[4];
    float bf = bfuse[c];
    #pragma unroll
    for (int j = 0; j < 4; ++j) acc[j] = bf;

    for (int i = 0; i < 2 * CC; i += 4) {
        float wv0 = Wfuse[(i + 0) * CC + c];
        float wv1 = Wfuse[(i + 1) * CC + c];
        float wv2 = Wfuse[(i + 2) * CC + c];
        float wv3 = Wfuse[(i + 3) * CC + c];
        #pragma unroll
        for (int j = 0; j < 4; ++j) {
            int ni = half * 4 + j;
            float4 hv = *reinterpret_cast<const float4*>(&hbuf[ni][i]);
            acc[j] = fmaf(hv.x, wv0, fmaf(hv.y, wv1,
                     fmaf(hv.z, wv2, fmaf(hv.w, wv3, acc[j]))));
        }
    }
    #pragma unroll
    for (int j = 0; j < 4; ++j) {
        int n = n0 + half * 4 + j;
        if (n < N) out[n * CC + c] = fmaxf(acc[j], 0.f);
    }
}

extern "C" void kernel_launch(void* const* d_in, const int* in_sizes, int n_in,
                              void* d_out, int out_size, void* d_ws, size_t ws_size,
                              hipStream_t stream) {
    const float* x      = (const float*)d_in[0];
    const int*   ei     = (const int*)d_in[1];
    const float* eattr  = (const float*)d_in[2];
    const float* Wsrc0  = (const float*)d_in[3];
    const float* bsrc0  = (const float*)d_in[4];
    const float* Wdst0  = (const float*)d_in[5];
    const float* bdst0  = (const float*)d_in[6];
    const float* Wedge0 = (const float*)d_in[7];
    const float* att0   = (const float*)d_in[8];
    const float* bias0  = (const float*)d_in[9];
    const float* Wres0  = (const float*)d_in[10];
    const float* Wsrc1  = (const float*)d_in[11];
    const float* bsrc1  = (const float*)d_in[12];
    const float* Wdst1  = (const float*)d_in[13];
    const float* bdst1  = (const float*)d_in[14];
    const float* Wedge1 = (const float*)d_in[15];
    const float* att1   = (const float*)d_in[16];
    const float* bias1  = (const float*)d_in[17];
    const float* Wres1  = (const float*)d_in[18];
    const float* Wfuse  = (const float*)d_in[19];
    const float* bfuse  = (const float*)d_in[20];
    float* out = (float*)d_out;

    int N = in_sizes[0] / 2;   // x is (N,2)
    int E = in_sizes[1] / 2;   // edge_index is (2,E)
    int Etot = E + N;

    // workspace layout (meansum+cnt adjacent for a single memset)
    size_t off = 0;
    float* meansum = (float*)((char*)d_ws + off);  off += 256;
    int*   cnt     = (int*)((char*)d_ws + off);    off += roundup256((size_t)N * sizeof(int));
    size_t zero_bytes = off;
    int*   cur     = (int*)((char*)d_ws + off);    off += roundup256((size_t)N * sizeof(int));
    int*   rowptr  = (int*)((char*)d_ws + off);    off += roundup256((size_t)(N + 1) * sizeof(int));
    float* packed  = (float*)((char*)d_ws + off);  off += roundup256(8 * 128 * 8 * sizeof(float));
    int4*  rec4    = (int4*)((char*)d_ws + off);   off += roundup256((size_t)Etot * sizeof(int4));
    float* p8      = (float*)((char*)d_ws + off);  off += roundup256((size_t)Etot * 8 * sizeof(float));
    float* S       = (float*)((char*)d_ws + off);  off += roundup256((size_t)24 * N * sizeof(float));

    hipMemsetAsync(d_ws, 0, zero_bytes, stream);

    prep_kernel<<<(E + 255) / 256, 256, 0, stream>>>(
        ei, eattr, meansum, cnt,
        Wsrc0, bsrc0, Wdst0, bdst0, Wedge0, att0,
        Wsrc1, bsrc1, Wdst1, bdst1, Wedge1, att1,
        packed, E);

    scan_kernel<<<1, 1024, 0, stream>>>(cnt, rowptr, cur, N);

    scatter_kernel<<<(Etot + 255) / 256, 256, 0, stream>>>(ei, cur, rec4, N, E);

    int nchunks = (Etot + 63) / 64;
    logits_kernel<<<(nchunks + 3) / 4, 256, 0, stream>>>(
        x, eattr, meansum, rec4, (const float4*)packed, p8, N, E);

    nodeS_kernel<<<(N + 31) / 32, 256, 0, stream>>>(x, rowptr, rec4, p8, S, N);

    node_kernel<<<(N + NPB - 1) / NPB, 256, 0, stream>>>(
        x, S,
        Wsrc0, bsrc0, bias0, Wres0,
        Wsrc1, bsrc1, bias1, Wres1,
        Wfuse, bfuse, out, N);
}